// Round 10
// baseline (318.367 us; speedup 1.0000x reference)
//
#include <hip/hip_runtime.h>
#include <hip/hip_bf16.h>
#include <math.h>

#define ALPHA 0.2f
#define NEGV  -9000000000000000.0f
#define EPSV  1e-5f

static constexpr int Bn = 8;
static constexpr int Nn = 1024;
static constexpr int Fn = 512;
static constexpr int M  = Bn * Nn;   // 8192 rows total

typedef __attribute__((ext_vector_type(8))) short bf16x8;
typedef __attribute__((ext_vector_type(4))) float f32x4;

__device__ inline float wave_reduce_sum(float v) {
#pragma unroll
    for (int off = 32; off; off >>= 1) v += __shfl_xor(v, off);
    return v;
}
__device__ inline float wave_reduce_max(float v) {
#pragma unroll
    for (int off = 32; off; off >>= 1) v = fmaxf(v, __shfl_xor(v, off));
    return v;
}

__device__ inline short f2bf(float f) {               // RNE via HW cvt (compiler pairs into cvt_pk)
    __hip_bfloat16 h = __float2bfloat16(f);
    return *reinterpret_cast<short*>(&h);
}
__device__ inline float bf2f(short s) {
    union { unsigned int u; float f; } v; v.u = (unsigned int)(unsigned short)s << 16;
    return v.f;
}

// ---------------------------------------------------------------------------
// K0: c1 = W1@a1, c2 = W2@a2 (tiny)
// ---------------------------------------------------------------------------
__global__ __launch_bounds__(64) void k_proj_w(const float* __restrict__ W1,
                                               const float* __restrict__ W2,
                                               const float* __restrict__ a,
                                               float* __restrict__ c) {
    int bid = blockIdx.x, which = bid >> 9, row = bid & 511;
    const float* W  = which ? W2 : W1;
    const float* av = a + which * Fn;
    const float* wr = W + (size_t)row * Fn;
    int lane = threadIdx.x;
    float s = 0.f;
#pragma unroll
    for (int p = 0; p < 2; ++p) {
        float4 wv = *(const float4*)&wr[lane * 4 + p * 256];
        float4 a4 = *(const float4*)&av[lane * 4 + p * 256];
        s += wv.x * a4.x + wv.y * a4.y + wv.z * a4.z + wv.w * a4.w;
    }
    s = wave_reduce_sum(s);
    if (lane == 0) c[which * Fn + row] = s;
}

// ---------------------------------------------------------------------------
// K1: Wha = h1@c1 ; Wta = h2@c2 (wave per row)
// ---------------------------------------------------------------------------
__global__ __launch_bounds__(256) void k_proj_h(const float* __restrict__ h1,
                                                const float* __restrict__ h2,
                                                const float* __restrict__ c,
                                                float* __restrict__ Wha,
                                                float* __restrict__ Wta) {
    int which = blockIdx.y;
    const float* h  = which ? h2 : h1;
    const float* cv = c + which * Fn;
    float* outp = which ? Wta : Wha;
    int wave = threadIdx.x >> 6, lane = threadIdx.x & 63;
    int row  = blockIdx.x * 4 + wave;
    const float* hr = h + (size_t)row * Fn;
    float s = 0.f;
#pragma unroll
    for (int p = 0; p < 2; ++p) {
        float4 hv = *(const float4*)&hr[lane * 8 + p * 4];
        float4 c4 = *(const float4*)&cv[lane * 8 + p * 4];
        s += hv.x * c4.x + hv.y * c4.y + hv.z * c4.z + hv.w * c4.w;
    }
    s = wave_reduce_sum(s);
    if (lane == 0) outp[row] = s;
}

// ---------------------------------------------------------------------------
// K2: fused adj-pack + softmax stats. One block per row (256 thr, 4 j each):
// reads adj row (4KB) once, emits pk row (32 words) + stat=(m, 1/s).
// ---------------------------------------------------------------------------
__global__ __launch_bounds__(256) void k_packstats(const int* __restrict__ adj,
                                                   const float* __restrict__ Wha,
                                                   const float* __restrict__ Wta,
                                                   unsigned int* __restrict__ pk,
                                                   float2* __restrict__ stat) {
    int bi = blockIdx.x;
    int b = bi >> 10;
    const int*   arow = adj + (size_t)bi * Nn;
    const float* wt   = Wta + b * Nn;
    float whai = Wha[bi];
    int t = threadIdx.x;
    int4   av = *(const int4*)&arow[t * 4];
    float4 wv = *(const float4*)&wt[t * 4];
    unsigned int nib = (unsigned)(av.x > 0) | ((unsigned)(av.y > 0) << 1) |
                       ((unsigned)(av.z > 0) << 2) | ((unsigned)(av.w > 0) << 3);
    float e[4];
    {
        float x;
        x = whai + wv.x; x = fmaxf(x, ALPHA * x); e[0] = (nib & 1) ? x : NEGV;
        x = whai + wv.y; x = fmaxf(x, ALPHA * x); e[1] = (nib & 2) ? x : NEGV;
        x = whai + wv.z; x = fmaxf(x, ALPHA * x); e[2] = (nib & 4) ? x : NEGV;
        x = whai + wv.w; x = fmaxf(x, ALPHA * x); e[3] = (nib & 8) ? x : NEGV;
    }
    __shared__ unsigned char nibs[256];
    __shared__ float redm[4], reds[4];
    nibs[t] = (unsigned char)nib;
    int wave = t >> 6, lane = t & 63;
    float m4 = fmaxf(fmaxf(e[0], e[1]), fmaxf(e[2], e[3]));
    float m = wave_reduce_max(m4);
    if (lane == 0) redm[wave] = m;
    __syncthreads();
    m = fmaxf(fmaxf(redm[0], redm[1]), fmaxf(redm[2], redm[3]));
    float s4 = __expf(e[0] - m) + __expf(e[1] - m) + __expf(e[2] - m) + __expf(e[3] - m);
    float s = wave_reduce_sum(s4);
    if (lane == 0) reds[wave] = s;
    __syncthreads();
    if (t < 32) {   // assemble packed words: word t covers j = 32t..32t+31
        unsigned int w = 0;
#pragma unroll
        for (int u = 0; u < 8; ++u) w |= ((unsigned int)nibs[t * 8 + u]) << (4 * u);
        pk[(size_t)bi * 32 + t] = w;
    }
    if (t == 0) {
        s = reds[0] + reds[1] + reds[2] + reds[3];
        stat[bi] = make_float2(m, 1.0f / s);
    }
}

// ---------------------------------------------------------------------------
// K3: w3T_hi/lo[f][k] = split(W3[k][f]) — 32x32 LDS tile transpose
// ---------------------------------------------------------------------------
__global__ __launch_bounds__(256) void k_w3t(const float* __restrict__ W3,
                                             unsigned short* __restrict__ hi,
                                             unsigned short* __restrict__ lo) {
    __shared__ float tile[32][33];
    int kt = blockIdx.x * 32, ft = blockIdx.y * 32;
    int c = threadIdx.x & 31, r = threadIdx.x >> 5;
#pragma unroll
    for (int s = 0; s < 4; ++s)
        tile[r + s * 8][c] = W3[(size_t)(kt + r + s * 8) * Fn + ft + c];
    __syncthreads();
#pragma unroll
    for (int s = 0; s < 4; ++s) {
        float f = tile[c][r + s * 8];
        short h = f2bf(f);
        size_t o = (size_t)(ft + r + s * 8) * Fn + kt + c;
        hi[o] = (unsigned short)h;
        lo[o] = (unsigned short)f2bf(f - bf2f(h));
    }
}

// ---------------------------------------------------------------------------
// K4: Wv = h2 @ W3, register-direct MFMA. Tile 64i x 64f, 4 waves (wave =
// 16 rows). grid (i=128, f=8): same-i f-blocks are bid i+128f: %8 = i%8
// const -> A-panel L2-shared per XCD. Output wvT[b][f][i] split hi/lo.
// ---------------------------------------------------------------------------
__global__ __launch_bounds__(256, 4) void k_gemm3(const float* __restrict__ h2,
                                                  const unsigned short* __restrict__ w3h,
                                                  const unsigned short* __restrict__ w3l,
                                                  unsigned short* __restrict__ wvh,
                                                  unsigned short* __restrict__ wvl) {
    __shared__ float etile[64 * 68];
    int t = threadIdx.x, wave = t >> 6, lane = t & 63;
    int l15 = lane & 15, l16 = lane >> 4;
    int i0 = blockIdx.x * 64, f0 = blockIdx.y * 64;

    f32x4 acc[4];
#pragma unroll
    for (int nj = 0; nj < 4; ++nj) acc[nj] = (f32x4){0.f, 0.f, 0.f, 0.f};

    const float* abase = h2 + (size_t)(i0 + wave * 16 + l15) * Fn + l16 * 8;
    const unsigned short* bhb = w3h + (size_t)(f0 + l15) * Fn + l16 * 8;
    const unsigned short* blb = w3l + (size_t)(f0 + l15) * Fn + l16 * 8;

#pragma unroll 2
    for (int kt = 0; kt < Fn / 32; ++kt) {
        bf16x8 bh[4], bl[4];
#pragma unroll
        for (int nj = 0; nj < 4; ++nj) {
            bh[nj] = *(const bf16x8*)(bhb + (size_t)nj * 16 * Fn + kt * 32);
            bl[nj] = *(const bf16x8*)(blb + (size_t)nj * 16 * Fn + kt * 32);
        }
        float4 v0 = *(const float4*)(abase + kt * 32);
        float4 v1 = *(const float4*)(abase + kt * 32 + 4);
        bf16x8 a0;
        a0[0] = f2bf(v0.x); a0[1] = f2bf(v0.y); a0[2] = f2bf(v0.z); a0[3] = f2bf(v0.w);
        a0[4] = f2bf(v1.x); a0[5] = f2bf(v1.y); a0[6] = f2bf(v1.z); a0[7] = f2bf(v1.w);
#pragma unroll
        for (int nj = 0; nj < 4; ++nj) {
            acc[nj] = __builtin_amdgcn_mfma_f32_16x16x32_bf16(a0, bh[nj], acc[nj], 0, 0, 0);
            acc[nj] = __builtin_amdgcn_mfma_f32_16x16x32_bf16(a0, bl[nj], acc[nj], 0, 0, 0);
        }
    }
    // epilogue: stage C to LDS [f][i], then coalesced split-bf16 writes of wvT
#pragma unroll
    for (int nj = 0; nj < 4; ++nj) {
        int floc = nj * 16 + l15;
        int nloc = wave * 16 + l16 * 4;
        *(f32x4*)&etile[floc * 68 + nloc] = acc[nj];
    }
    __syncthreads();
    {
        int floc = t >> 2, ic = (t & 3) * 16;
        int b = i0 >> 10, nb = (i0 & 1023) + ic;
        const float* src = &etile[floc * 68 + ic];
        unsigned short* oh = wvh + ((size_t)b * Fn + f0 + floc) * Nn + nb;
        unsigned short* ol = wvl + ((size_t)b * Fn + f0 + floc) * Nn + nb;
        bf16x8 rh0, rh1, rl0, rl1;
#pragma unroll
        for (int q = 0; q < 8; ++q) {
            float f0v = src[q], f1v = src[8 + q];
            short h0 = f2bf(f0v), h1 = f2bf(f1v);
            rh0[q] = h0; rh1[q] = h1;
            rl0[q] = f2bf(f0v - bf2f(h0));
            rl1[q] = f2bf(f1v - bf2f(h1));
        }
        *(bf16x8*)oh = rh0; *(bf16x8*)(oh + 8) = rh1;
        *(bf16x8*)ol = rl0; *(bf16x8*)(ol + 8) = rl1;
    }
}

// ---------------------------------------------------------------------------
// K5: h' = attention @ Wv, register-direct MFMA, tile 64i x 64f, 4 waves
// (wave = 16 rows; lane owns att row m=l15, k-slice l16*8). A generated
// in-register from LDS pk/wta/stats (row params hoisted — fixed per lane).
// B direct 16B loads from wvT. grid (f=8, i=16, b=8): bid%8 = f -> all
// i-blocks sharing a (b,f) wvT panel land on one XCD.
// ---------------------------------------------------------------------------
__global__ __launch_bounds__(256, 4) void k_attn3(const unsigned int* __restrict__ pk,
                                                  const float* __restrict__ Wha,
                                                  const float* __restrict__ Wta,
                                                  const float2* __restrict__ stat,
                                                  const unsigned short* __restrict__ wvh,
                                                  const unsigned short* __restrict__ wvl,
                                                  float* __restrict__ outp) {
    __shared__ unsigned int pkt[32 * 64];   // [word][row]
    __shared__ float wta_s[Nn];
    __shared__ float wha_s[64], m_s[64], rs_s[64];
    int t = threadIdx.x, wave = t >> 6, lane = t & 63;
    int l15 = lane & 15, l16 = lane >> 4;
    int f0 = blockIdx.x * 64, i0 = blockIdx.y * 64, b = blockIdx.z;

    {   // stage pk transposed: thread (r = t&63, wq = t>>6) copies 8 words
        int r = t & 63, wq = t >> 6;
        const unsigned int* src = pk + (size_t)(b * Nn + i0 + r) * 32 + wq * 8;
        uint4 u0 = *(const uint4*)src, u1 = *(const uint4*)(src + 4);
        pkt[(wq * 8 + 0) * 64 + r] = u0.x; pkt[(wq * 8 + 1) * 64 + r] = u0.y;
        pkt[(wq * 8 + 2) * 64 + r] = u0.z; pkt[(wq * 8 + 3) * 64 + r] = u0.w;
        pkt[(wq * 8 + 4) * 64 + r] = u1.x; pkt[(wq * 8 + 5) * 64 + r] = u1.y;
        pkt[(wq * 8 + 6) * 64 + r] = u1.z; pkt[(wq * 8 + 7) * 64 + r] = u1.w;
        *(float4*)&wta_s[t * 4] = *(const float4*)&Wta[b * Nn + t * 4];
        if (t < 64) {
            wha_s[t] = Wha[b * Nn + i0 + t];
            float2 st = stat[b * Nn + i0 + t];
            m_s[t] = st.x; rs_s[t] = st.y;
        }
    }
    __syncthreads();

    // hoisted per-lane row params (att row = wave*16 + l15, fixed)
    float whaA = wha_s[wave * 16 + l15];
    float mA   = m_s[wave * 16 + l15];
    const unsigned short* bhb = wvh + ((size_t)b * Fn + f0 + l15) * Nn + l16 * 8;
    const unsigned short* blb = wvl + ((size_t)b * Fn + f0 + l15) * Nn + l16 * 8;

    f32x4 acc[4];
#pragma unroll
    for (int nj = 0; nj < 4; ++nj) acc[nj] = (f32x4){0.f, 0.f, 0.f, 0.f};

#pragma unroll 2
    for (int kt = 0; kt < Nn / 32; ++kt) {
        bf16x8 bh[4], bl[4];
#pragma unroll
        for (int nj = 0; nj < 4; ++nj) {
            bh[nj] = *(const bf16x8*)(bhb + (size_t)nj * 16 * Nn + kt * 32);
            bl[nj] = *(const bf16x8*)(blb + (size_t)nj * 16 * Nn + kt * 32);
        }
        unsigned int sh = pkt[kt * 64 + wave * 16 + l15] >> (l16 * 8);
        float4 wq0 = *(const float4*)&wta_s[kt * 32 + l16 * 8];
        float4 wq1 = *(const float4*)&wta_s[kt * 32 + l16 * 8 + 4];
        float wq[8] = {wq0.x, wq0.y, wq0.z, wq0.w, wq1.x, wq1.y, wq1.z, wq1.w};
        bf16x8 a0;
#pragma unroll
        for (int q = 0; q < 8; ++q) {
            float x = whaA + wq[q];
            x = fmaxf(x, ALPHA * x);
            float p = __expf(x - mA);
            p = ((sh >> q) & 1) ? p : 0.0f;
            a0[q] = f2bf(p);
        }
#pragma unroll
        for (int nj = 0; nj < 4; ++nj) {
            acc[nj] = __builtin_amdgcn_mfma_f32_16x16x32_bf16(a0, bh[nj], acc[nj], 0, 0, 0);
            acc[nj] = __builtin_amdgcn_mfma_f32_16x16x32_bf16(a0, bl[nj], acc[nj], 0, 0, 0);
        }
    }
    // epilogue: scale by 1/s (C row = wave*16 + l16*4 + r), store fp32
#pragma unroll
    for (int nj = 0; nj < 4; ++nj) {
#pragma unroll
        for (int r = 0; r < 4; ++r) {
            int rloc = wave * 16 + l16 * 4 + r;
            outp[((size_t)b * Nn + i0 + rloc) * Fn + f0 + nj * 16 + l15] =
                rs_s[rloc] * acc[nj][r];
        }
    }
}

// ---------------------------------------------------------------------------
// K6: LayerNorm over F + exact GELU, in-place on d_out. grid M x 128
// ---------------------------------------------------------------------------
__global__ __launch_bounds__(128) void k_ln_gelu(float* __restrict__ x,
                                                 const float* __restrict__ gamma,
                                                 const float* __restrict__ beta) {
    int row = blockIdx.x;
    float* xr = x + (size_t)row * Fn;
    int t = threadIdx.x;
    float4 v = *(float4*)&xr[t * 4];
    float s = v.x + v.y + v.z + v.w;
    float q = v.x * v.x + v.y * v.y + v.z * v.z + v.w * v.w;
    s = wave_reduce_sum(s);
    q = wave_reduce_sum(q);
    __shared__ float rs[2], rq[2];
    int wave = t >> 6, lane = t & 63;
    if (lane == 0) { rs[wave] = s; rq[wave] = q; }
    __syncthreads();
    s = rs[0] + rs[1];
    q = rq[0] + rq[1];
    float mu   = s * (1.0f / Fn);
    float var  = q * (1.0f / Fn) - mu * mu;
    float rstd = rsqrtf(var + EPSV);
    float4 g  = *(const float4*)&gamma[t * 4];
    float4 be = *(const float4*)&beta[t * 4];
    auto gel = [](float xx) { return 0.5f * xx * (1.0f + erff(xx * 0.70710678118f)); };
    float y0 = (v.x - mu) * rstd * g.x + be.x;
    float y1 = (v.y - mu) * rstd * g.y + be.y;
    float y2 = (v.z - mu) * rstd * g.z + be.z;
    float y3 = (v.w - mu) * rstd * g.w + be.w;
    float4 o = {gel(y0), gel(y1), gel(y2), gel(y3)};
    *(float4*)&xr[t * 4] = o;
}

// ---------------------------------------------------------------------------
extern "C" void kernel_launch(void* const* d_in, const int* in_sizes, int n_in,
                              void* d_out, int out_size, void* d_ws, size_t ws_size,
                              hipStream_t stream) {
    const float* h1    = (const float*)d_in[0];
    const float* h2    = (const float*)d_in[1];
    const int*   adj   = (const int*)d_in[2];
    const float* W1    = (const float*)d_in[3];
    const float* W2    = (const float*)d_in[4];
    const float* W3    = (const float*)d_in[5];
    const float* a     = (const float*)d_in[6];
    const float* gamma = (const float*)d_in[7];
    const float* beta  = (const float*)d_in[8];
    float* outp = (float*)d_out;

    // workspace (~19 MB): wvT hi/lo | w3T hi/lo | pack | stat | c | Wha | Wta
    unsigned short* wvh  = (unsigned short*)d_ws;
    unsigned short* wvl  = wvh + (size_t)M * Fn;
    unsigned short* w3h  = wvl + (size_t)M * Fn;
    unsigned short* w3l  = w3h + (size_t)Fn * Fn;
    unsigned int*   pack = (unsigned int*)(w3l + (size_t)Fn * Fn);
    float2*         stat = (float2*)(pack + (size_t)M * 32);
    float*          c    = (float*)(stat + M);
    float*          Wha  = c + 1024;
    float*          Wta  = Wha + M;

    hipLaunchKernelGGL(k_proj_w, dim3(1024), dim3(64), 0, stream, W1, W2, a, c);
    hipLaunchKernelGGL(k_proj_h, dim3(M / 4, 2), dim3(256), 0, stream, h1, h2, c, Wha, Wta);
    hipLaunchKernelGGL(k_packstats, dim3(M), dim3(256), 0, stream, adj, Wha, Wta, pack, stat);
    hipLaunchKernelGGL(k_w3t, dim3(16, 16), dim3(256), 0, stream, W3, w3h, w3l);
    hipLaunchKernelGGL(k_gemm3, dim3(M / 64, Fn / 64), dim3(256), 0, stream,
                       h2, w3h, w3l, wvh, wvl);
    hipLaunchKernelGGL(k_attn3, dim3(Fn / 64, Nn / 64, Bn), dim3(256), 0, stream,
                       pack, Wha, Wta, stat, wvh, wvl, outp);
    hipLaunchKernelGGL(k_ln_gelu, dim3(M), dim3(128), 0, stream, outp, gamma, beta);
}

// Round 14
// 266.029 us; speedup vs baseline: 1.1967x; 1.1967x over previous
//
#include <hip/hip_runtime.h>
#include <hip/hip_bf16.h>
#include <math.h>

#define ALPHA 0.2f
#define NEGV  -9000000000000000.0f
#define EPSV  1e-5f

static constexpr int Bn = 8;
static constexpr int Nn = 1024;
static constexpr int Fn = 512;
static constexpr int M  = Bn * Nn;   // 8192 rows total

typedef __attribute__((ext_vector_type(8))) short bf16x8;
typedef __attribute__((ext_vector_type(4))) float f32x4;

__device__ inline float wave_reduce_sum(float v) {
#pragma unroll
    for (int off = 32; off; off >>= 1) v += __shfl_xor(v, off);
    return v;
}
__device__ inline float wave_reduce_max(float v) {
#pragma unroll
    for (int off = 32; off; off >>= 1) v = fmaxf(v, __shfl_xor(v, off));
    return v;
}

__device__ inline short f2bf(float f) {
    __hip_bfloat16 h = __float2bfloat16(f);
    return *reinterpret_cast<short*>(&h);
}
__device__ inline float bf2f(short s) {
    union { unsigned int u; float f; } v; v.u = (unsigned int)(unsigned short)s << 16;
    return v.f;
}

// ---------------------------------------------------------------------------
// K0: c1 = W1@a1, c2 = W2@a2 (tiny)
// ---------------------------------------------------------------------------
__global__ __launch_bounds__(64) void k_proj_w(const float* __restrict__ W1,
                                               const float* __restrict__ W2,
                                               const float* __restrict__ a,
                                               float* __restrict__ c) {
    int bid = blockIdx.x, which = bid >> 9, row = bid & 511;
    const float* W  = which ? W2 : W1;
    const float* av = a + which * Fn;
    const float* wr = W + (size_t)row * Fn;
    int lane = threadIdx.x;
    float s = 0.f;
#pragma unroll
    for (int p = 0; p < 2; ++p) {
        float4 wv = *(const float4*)&wr[lane * 4 + p * 256];
        float4 a4 = *(const float4*)&av[lane * 4 + p * 256];
        s += wv.x * a4.x + wv.y * a4.y + wv.z * a4.z + wv.w * a4.w;
    }
    s = wave_reduce_sum(s);
    if (lane == 0) c[which * Fn + row] = s;
}

// ---------------------------------------------------------------------------
// K1: Wha = h1@c1 ; Wta = h2@c2 (wave per row)
// ---------------------------------------------------------------------------
__global__ __launch_bounds__(256) void k_proj_h(const float* __restrict__ h1,
                                                const float* __restrict__ h2,
                                                const float* __restrict__ c,
                                                float* __restrict__ Wha,
                                                float* __restrict__ Wta) {
    int which = blockIdx.y;
    const float* h  = which ? h2 : h1;
    const float* cv = c + which * Fn;
    float* outp = which ? Wta : Wha;
    int wave = threadIdx.x >> 6, lane = threadIdx.x & 63;
    int row  = blockIdx.x * 4 + wave;
    const float* hr = h + (size_t)row * Fn;
    float s = 0.f;
#pragma unroll
    for (int p = 0; p < 2; ++p) {
        float4 hv = *(const float4*)&hr[lane * 8 + p * 4];
        float4 c4 = *(const float4*)&cv[lane * 8 + p * 4];
        s += hv.x * c4.x + hv.y * c4.y + hv.z * c4.z + hv.w * c4.w;
    }
    s = wave_reduce_sum(s);
    if (lane == 0) outp[row] = s;
}

// ---------------------------------------------------------------------------
// K2: fused adj-pack + softmax stats. One block per row.
// ---------------------------------------------------------------------------
__global__ __launch_bounds__(256) void k_packstats(const int* __restrict__ adj,
                                                   const float* __restrict__ Wha,
                                                   const float* __restrict__ Wta,
                                                   unsigned int* __restrict__ pk,
                                                   float2* __restrict__ stat) {
    int bi = blockIdx.x;
    int b = bi >> 10;
    const int*   arow = adj + (size_t)bi * Nn;
    const float* wt   = Wta + b * Nn;
    float whai = Wha[bi];
    int t = threadIdx.x;
    int4   av = *(const int4*)&arow[t * 4];
    float4 wv = *(const float4*)&wt[t * 4];
    unsigned int nib = (unsigned)(av.x > 0) | ((unsigned)(av.y > 0) << 1) |
                       ((unsigned)(av.z > 0) << 2) | ((unsigned)(av.w > 0) << 3);
    float e[4];
    {
        float x;
        x = whai + wv.x; x = fmaxf(x, ALPHA * x); e[0] = (nib & 1) ? x : NEGV;
        x = whai + wv.y; x = fmaxf(x, ALPHA * x); e[1] = (nib & 2) ? x : NEGV;
        x = whai + wv.z; x = fmaxf(x, ALPHA * x); e[2] = (nib & 4) ? x : NEGV;
        x = whai + wv.w; x = fmaxf(x, ALPHA * x); e[3] = (nib & 8) ? x : NEGV;
    }
    __shared__ unsigned char nibs[256];
    __shared__ float redm[4], reds[4];
    nibs[t] = (unsigned char)nib;
    int wave = t >> 6, lane = t & 63;
    float m4 = fmaxf(fmaxf(e[0], e[1]), fmaxf(e[2], e[3]));
    float m = wave_reduce_max(m4);
    if (lane == 0) redm[wave] = m;
    __syncthreads();
    m = fmaxf(fmaxf(redm[0], redm[1]), fmaxf(redm[2], redm[3]));
    float s4 = __expf(e[0] - m) + __expf(e[1] - m) + __expf(e[2] - m) + __expf(e[3] - m);
    float s = wave_reduce_sum(s4);
    if (lane == 0) reds[wave] = s;
    __syncthreads();
    if (t < 32) {
        unsigned int w = 0;
#pragma unroll
        for (int u = 0; u < 8; ++u) w |= ((unsigned int)nibs[t * 8 + u]) << (4 * u);
        pk[(size_t)bi * 32 + t] = w;
    }
    if (t == 0) {
        s = reds[0] + reds[1] + reds[2] + reds[3];
        stat[bi] = make_float2(m, 1.0f / s);
    }
}

// ---------------------------------------------------------------------------
// K3: w3T_hi/lo[f][k] = split(W3[k][f])
// ---------------------------------------------------------------------------
__global__ __launch_bounds__(256) void k_w3t(const float* __restrict__ W3,
                                             unsigned short* __restrict__ hi,
                                             unsigned short* __restrict__ lo) {
    __shared__ float tile[32][33];
    int kt = blockIdx.x * 32, ft = blockIdx.y * 32;
    int c = threadIdx.x & 31, r = threadIdx.x >> 5;
#pragma unroll
    for (int s = 0; s < 4; ++s)
        tile[r + s * 8][c] = W3[(size_t)(kt + r + s * 8) * Fn + ft + c];
    __syncthreads();
#pragma unroll
    for (int s = 0; s < 4; ++s) {
        float f = tile[c][r + s * 8];
        short h = f2bf(f);
        size_t o = (size_t)(ft + r + s * 8) * Fn + kt + c;
        hi[o] = (unsigned short)h;
        lo[o] = (unsigned short)f2bf(f - bf2f(h));
    }
}

// ---------------------------------------------------------------------------
// K4: Wv = h2 @ W3, register-direct MFMA. Tile 64i x 128f, 4 waves (wave =
// 16 rows x 128 f = 8 independent n-chains). A (h2) prefetched one kt ahead;
// B (w3T, 1MB total) is L2-resident. grid (i=128, f=4): same-i f-blocks at
// bid%8 = i%8 -> one XCD's L2 serves all 4 f-blocks' h2 panel (h2 HBM ~1x).
// Output wvT[b][f][i] split hi/lo via LDS-bounce epilogue.
// ---------------------------------------------------------------------------
__global__ __launch_bounds__(256) void k_gemm4(const float* __restrict__ h2,
                                               const unsigned short* __restrict__ w3h,
                                               const unsigned short* __restrict__ w3l,
                                               unsigned short* __restrict__ wvh,
                                               unsigned short* __restrict__ wvl) {
    __shared__ float etile[128 * 68];
    int t = threadIdx.x, wave = t >> 6, lane = t & 63;
    int l15 = lane & 15, l16 = lane >> 4;
    int i0 = blockIdx.x * 64, f0 = blockIdx.y * 128;

    f32x4 acc[8];
#pragma unroll
    for (int nj = 0; nj < 8; ++nj) acc[nj] = (f32x4){0.f, 0.f, 0.f, 0.f};

    const float* abase = h2 + (size_t)(i0 + wave * 16 + l15) * Fn + l16 * 8;
    const unsigned short* bhb = w3h + (size_t)(f0 + l15) * Fn + l16 * 8;
    const unsigned short* blb = w3l + (size_t)(f0 + l15) * Fn + l16 * 8;

    const int NKT = Fn / 32;   // 16
    float4 va0 = *(const float4*)(abase);
    float4 va1 = *(const float4*)(abase + 4);
    for (int kt = 0; kt < NKT; ++kt) {
        int ktn = (kt + 1 < NKT) ? kt + 1 : kt;
        float4 na0 = *(const float4*)(abase + ktn * 32);
        float4 na1 = *(const float4*)(abase + ktn * 32 + 4);
        bf16x8 bh[8], bl[8];
#pragma unroll
        for (int nj = 0; nj < 8; ++nj) {
            bh[nj] = *(const bf16x8*)(bhb + (size_t)nj * 16 * Fn + kt * 32);
            bl[nj] = *(const bf16x8*)(blb + (size_t)nj * 16 * Fn + kt * 32);
        }
        bf16x8 a0;
        a0[0] = f2bf(va0.x); a0[1] = f2bf(va0.y); a0[2] = f2bf(va0.z); a0[3] = f2bf(va0.w);
        a0[4] = f2bf(va1.x); a0[5] = f2bf(va1.y); a0[6] = f2bf(va1.z); a0[7] = f2bf(va1.w);
#pragma unroll
        for (int nj = 0; nj < 8; ++nj) {
            acc[nj] = __builtin_amdgcn_mfma_f32_16x16x32_bf16(a0, bh[nj], acc[nj], 0, 0, 0);
            acc[nj] = __builtin_amdgcn_mfma_f32_16x16x32_bf16(a0, bl[nj], acc[nj], 0, 0, 0);
        }
        va0 = na0; va1 = na1;
    }
    // epilogue: stage C to LDS [f][i], then coalesced split-bf16 writes of wvT
#pragma unroll
    for (int nj = 0; nj < 8; ++nj) {
        int floc = nj * 16 + l15;
        int iloc = wave * 16 + l16 * 4;
        *(f32x4*)&etile[floc * 68 + iloc] = acc[nj];
    }
    __syncthreads();
    {
        int floc = t >> 1, ih = (t & 1) * 32;
        int b = i0 >> 10, nb = (i0 & 1023) + ih;
        const float* src = &etile[floc * 68 + ih];
        unsigned short* oh = wvh + ((size_t)b * Fn + f0 + floc) * Nn + nb;
        unsigned short* ol = wvl + ((size_t)b * Fn + f0 + floc) * Nn + nb;
#pragma unroll
        for (int s = 0; s < 4; ++s) {
            bf16x8 rh, rl;
#pragma unroll
            for (int q = 0; q < 8; ++q) {
                float f = src[s * 8 + q];
                short h = f2bf(f);
                rh[q] = h;
                rl[q] = f2bf(f - bf2f(h));
            }
            *(bf16x8*)(oh + s * 8) = rh;
            *(bf16x8*)(ol + s * 8) = rl;
        }
    }
}

// ---------------------------------------------------------------------------
// K5: h' = attention @ Wv, register-direct MFMA. Tile 128i x 64f, 4 waves
// (wave = 32 rows = 2 m-frags -> 2 independent MFMA chains). A generated
// in-register (lane owns rows w*32+l15 and w*32+16+l15, k-slice l16*8); B
// (wvT) double-buffered in registers: next kt's 8 fragments load during
// current MFMAs. grid (f=8, i=8, b=8): bid%8 = f -> all (b,i) blocks of one
// f-slice share an XCD L2.
// ---------------------------------------------------------------------------
__global__ __launch_bounds__(256) void k_attn4(const unsigned int* __restrict__ pk,
                                               const float* __restrict__ Wha,
                                               const float* __restrict__ Wta,
                                               const float2* __restrict__ stat,
                                               const unsigned short* __restrict__ wvh,
                                               const unsigned short* __restrict__ wvl,
                                               float* __restrict__ outp) {
    __shared__ unsigned int pkt[32 * 128];   // [word][row]
    __shared__ float wta_s[Nn];
    __shared__ float wha_s[128], m_s[128], rs_s[128];
    int t = threadIdx.x, wave = t >> 6, lane = t & 63;
    int l15 = lane & 15, l16 = lane >> 4;
    int f0 = blockIdx.x * 64, i0 = blockIdx.y * 128, b = blockIdx.z;

    {   // stage pk transposed: thread (r = t>>1, half = t&1) copies 16 words
        int r = t >> 1, half = t & 1;
        const unsigned int* src = pk + (size_t)(b * Nn + i0 + r) * 32 + half * 16;
        uint4 u0 = *(const uint4*)src, u1 = *(const uint4*)(src + 4);
        uint4 u2 = *(const uint4*)(src + 8), u3 = *(const uint4*)(src + 12);
        unsigned int wv_[16] = {u0.x, u0.y, u0.z, u0.w, u1.x, u1.y, u1.z, u1.w,
                                u2.x, u2.y, u2.z, u2.w, u3.x, u3.y, u3.z, u3.w};
#pragma unroll
        for (int w = 0; w < 16; ++w) pkt[(half * 16 + w) * 128 + r] = wv_[w];
        *(float4*)&wta_s[t * 4] = *(const float4*)&Wta[b * Nn + t * 4];
        if (t < 128) {
            wha_s[t] = Wha[b * Nn + i0 + t];
            float2 st = stat[b * Nn + i0 + t];
            m_s[t] = st.x; rs_s[t] = st.y;
        }
    }
    __syncthreads();

    float whaA = wha_s[wave * 32 + l15],      mA = m_s[wave * 32 + l15];
    float whaB = wha_s[wave * 32 + 16 + l15], mB = m_s[wave * 32 + 16 + l15];
    const unsigned short* bhb = wvh + ((size_t)b * Fn + f0 + l15) * Nn + l16 * 8;
    const unsigned short* blb = wvl + ((size_t)b * Fn + f0 + l15) * Nn + l16 * 8;

    f32x4 acc[2][4];
#pragma unroll
    for (int mi = 0; mi < 2; ++mi)
#pragma unroll
        for (int nj = 0; nj < 4; ++nj) acc[mi][nj] = (f32x4){0.f, 0.f, 0.f, 0.f};

    const int NKT = Nn / 32;   // 32
    bf16x8 bh[4], bl[4];
#pragma unroll
    for (int nj = 0; nj < 4; ++nj) {
        bh[nj] = *(const bf16x8*)(bhb + (size_t)nj * 16 * Nn);
        bl[nj] = *(const bf16x8*)(blb + (size_t)nj * 16 * Nn);
    }
    for (int kt = 0; kt < NKT; ++kt) {
        int ktn = (kt + 1 < NKT) ? kt + 1 : kt;
        bf16x8 nh[4], nl[4];
#pragma unroll
        for (int nj = 0; nj < 4; ++nj) {
            nh[nj] = *(const bf16x8*)(bhb + (size_t)nj * 16 * Nn + ktn * 32);
            nl[nj] = *(const bf16x8*)(blb + (size_t)nj * 16 * Nn + ktn * 32);
        }
        // att-gen for both rows (independent of the loads above)
        unsigned int shA = pkt[kt * 128 + wave * 32 + l15] >> (l16 * 8);
        unsigned int shB = pkt[kt * 128 + wave * 32 + 16 + l15] >> (l16 * 8);
        float4 wq0 = *(const float4*)&wta_s[kt * 32 + l16 * 8];
        float4 wq1 = *(const float4*)&wta_s[kt * 32 + l16 * 8 + 4];
        float wq[8] = {wq0.x, wq0.y, wq0.z, wq0.w, wq1.x, wq1.y, wq1.z, wq1.w};
        bf16x8 a0, a1;
#pragma unroll
        for (int q = 0; q < 8; ++q) {
            float xA = whaA + wq[q];
            xA = fmaxf(xA, ALPHA * xA);
            float pA = __expf(xA - mA);
            pA = ((shA >> q) & 1) ? pA : 0.0f;
            a0[q] = f2bf(pA);
            float xB = whaB + wq[q];
            xB = fmaxf(xB, ALPHA * xB);
            float pB = __expf(xB - mB);
            pB = ((shB >> q) & 1) ? pB : 0.0f;
            a1[q] = f2bf(pB);
        }
#pragma unroll
        for (int nj = 0; nj < 4; ++nj) {
            acc[0][nj] = __builtin_amdgcn_mfma_f32_16x16x32_bf16(a0, bh[nj], acc[0][nj], 0, 0, 0);
            acc[0][nj] = __builtin_amdgcn_mfma_f32_16x16x32_bf16(a0, bl[nj], acc[0][nj], 0, 0, 0);
            acc[1][nj] = __builtin_amdgcn_mfma_f32_16x16x32_bf16(a1, bh[nj], acc[1][nj], 0, 0, 0);
            acc[1][nj] = __builtin_amdgcn_mfma_f32_16x16x32_bf16(a1, bl[nj], acc[1][nj], 0, 0, 0);
        }
#pragma unroll
        for (int nj = 0; nj < 4; ++nj) { bh[nj] = nh[nj]; bl[nj] = nl[nj]; }
    }
    // epilogue: scale by 1/s, store fp32
#pragma unroll
    for (int mi = 0; mi < 2; ++mi)
#pragma unroll
        for (int nj = 0; nj < 4; ++nj) {
#pragma unroll
            for (int r = 0; r < 4; ++r) {
                int rloc = wave * 32 + mi * 16 + l16 * 4 + r;
                outp[((size_t)b * Nn + i0 + rloc) * Fn + f0 + nj * 16 + l15] =
                    rs_s[rloc] * acc[mi][nj][r];
            }
        }
}

// ---------------------------------------------------------------------------
// K6: LayerNorm over F + exact GELU, in-place on d_out. grid M x 128
// ---------------------------------------------------------------------------
__global__ __launch_bounds__(128) void k_ln_gelu(float* __restrict__ x,
                                                 const float* __restrict__ gamma,
                                                 const float* __restrict__ beta) {
    int row = blockIdx.x;
    float* xr = x + (size_t)row * Fn;
    int t = threadIdx.x;
    float4 v = *(float4*)&xr[t * 4];
    float s = v.x + v.y + v.z + v.w;
    float q = v.x * v.x + v.y * v.y + v.z * v.z + v.w * v.w;
    s = wave_reduce_sum(s);
    q = wave_reduce_sum(q);
    __shared__ float rs[2], rq[2];
    int wave = t >> 6, lane = t & 63;
    if (lane == 0) { rs[wave] = s; rq[wave] = q; }
    __syncthreads();
    s = rs[0] + rs[1];
    q = rq[0] + rq[1];
    float mu   = s * (1.0f / Fn);
    float var  = q * (1.0f / Fn) - mu * mu;
    float rstd = rsqrtf(var + EPSV);
    float4 g  = *(const float4*)&gamma[t * 4];
    float4 be = *(const float4*)&beta[t * 4];
    auto gel = [](float xx) { return 0.5f * xx * (1.0f + erff(xx * 0.70710678118f)); };
    float y0 = (v.x - mu) * rstd * g.x + be.x;
    float y1 = (v.y - mu) * rstd * g.y + be.y;
    float y2 = (v.z - mu) * rstd * g.z + be.z;
    float y3 = (v.w - mu) * rstd * g.w + be.w;
    float4 o = {gel(y0), gel(y1), gel(y2), gel(y3)};
    *(float4*)&xr[t * 4] = o;
}

// ---------------------------------------------------------------------------
extern "C" void kernel_launch(void* const* d_in, const int* in_sizes, int n_in,
                              void* d_out, int out_size, void* d_ws, size_t ws_size,
                              hipStream_t stream) {
    const float* h1    = (const float*)d_in[0];
    const float* h2    = (const float*)d_in[1];
    const int*   adj   = (const int*)d_in[2];
    const float* W1    = (const float*)d_in[3];
    const float* W2    = (const float*)d_in[4];
    const float* W3    = (const float*)d_in[5];
    const float* a     = (const float*)d_in[6];
    const float* gamma = (const float*)d_in[7];
    const float* beta  = (const float*)d_in[8];
    float* outp = (float*)d_out;

    // workspace (~19 MB): wvT hi/lo | w3T hi/lo | pack | stat | c | Wha | Wta
    unsigned short* wvh  = (unsigned short*)d_ws;
    unsigned short* wvl  = wvh + (size_t)M * Fn;
    unsigned short* w3h  = wvl + (size_t)M * Fn;
    unsigned short* w3l  = w3h + (size_t)Fn * Fn;
    unsigned int*   pack = (unsigned int*)(w3l + (size_t)Fn * Fn);
    float2*         stat = (float2*)(pack + (size_t)M * 32);
    float*          c    = (float*)(stat + M);
    float*          Wha  = c + 1024;
    float*          Wta  = Wha + M;

    hipLaunchKernelGGL(k_proj_w, dim3(1024), dim3(64), 0, stream, W1, W2, a, c);
    hipLaunchKernelGGL(k_proj_h, dim3(M / 4, 2), dim3(256), 0, stream, h1, h2, c, Wha, Wta);
    hipLaunchKernelGGL(k_packstats, dim3(M), dim3(256), 0, stream, adj, Wha, Wta, pack, stat);
    hipLaunchKernelGGL(k_w3t, dim3(16, 16), dim3(256), 0, stream, W3, w3h, w3l);
    hipLaunchKernelGGL(k_gemm4, dim3(M / 64, Fn / 128), dim3(256), 0, stream,
                       h2, w3h, w3l, wvh, wvl);
    hipLaunchKernelGGL(k_attn4, dim3(Fn / 64, Nn / 128, Bn), dim3(256), 0, stream,
                       pack, Wha, Wta, stat, wvh, wvl, outp);
    hipLaunchKernelGGL(k_ln_gelu, dim3(M), dim3(128), 0, stream, outp, gamma, beta);
}